// Round 8
// baseline (44.168 us; speedup 1.0000x reference)
//
#include <hip/hip_runtime.h>

// TotalVariation over [32,8,3,256,256] f32 = 768 images of 256x256.
// tv = (sum|dh+eps| + sum|dw+eps|) / N, N = 50331648.
//
// Strip kernel: each 64-lane wave owns a 64-row strip of one image; a
// row is exactly 64 float4s -> one wave-wide coalesced 1KB load per
// row. Walking down keeps the previous row in registers; horizontal
// cross-float4 diff via __shfl_down. Branch-free body, unroll 4
// (unroll 8 regressed in R4). Each block does ONE plain atomicAdd of
// its pre-divided double partial into d_out (memory-side atomic, no
// __threadfence -- R5 proved fences in the hot kernel collapse BW).
// A 4-byte memset node zeroes d_out each call (replays would otherwise
// accumulate).

#define EPS 1e-6f

static constexpr long long NTOT = 32LL * 8 * 3 * 256 * 256;  // 50,331,648
static constexpr int RPS    = 64;                  // rows per strip
static constexpr int STRIPS = 768 * (256 / RPS);   // 3072
static constexpr int WPB    = 4;                   // waves per block
static constexpr int BLOCKS = STRIPS / WPB;        // 768 = 3 blocks/CU

__global__ void __launch_bounds__(256)
tv_strip_kernel(const float* __restrict__ x, float* __restrict__ out) {
    const int wid   = threadIdx.x >> 6;
    const int lane  = threadIdx.x & 63;
    const int strip = blockIdx.x * WPB + wid;        // 0 .. 3071
    const int img   = strip >> 2;                    // 4 strips per image
    const int r0    = (strip & 3) << 6;              // first row of strip

    const float* p = x + (size_t)img * 65536 + (size_t)r0 * 256 + lane * 4;

    float acc = 0.0f;
    float4 a = *reinterpret_cast<const float4*>(p);

    // rows r0+1 .. r0+63 are always inside the image: branch-free body.
    #pragma unroll 4
    for (int k = 1; k < RPS; ++k) {
        const float4 b = *reinterpret_cast<const float4*>(p + k * 256);
        // horizontal diffs for row r0+k-1
        acc += fabsf(a.y - a.x + EPS);
        acc += fabsf(a.z - a.y + EPS);
        acc += fabsf(a.w - a.z + EPS);
        const float nx = __shfl_down(a.x, 1, 64);    // neighbor float4's .x
        if (lane < 63) acc += fabsf(nx - a.w + EPS); // lane 63 = row end
        // vertical diffs row r0+k-1 -> r0+k
        acc += fabsf(b.x - a.x + EPS);
        acc += fabsf(b.y - a.y + EPS);
        acc += fabsf(b.z - a.z + EPS);
        acc += fabsf(b.w - a.w + EPS);
        a = b;
    }

    // epilogue: last row of the strip (r0+63)
    acc += fabsf(a.y - a.x + EPS);
    acc += fabsf(a.z - a.y + EPS);
    acc += fabsf(a.w - a.z + EPS);
    {
        const float nx = __shfl_down(a.x, 1, 64);
        if (lane < 63) acc += fabsf(nx - a.w + EPS);
    }
    // vertical diff into the next strip's first row, unless this is the
    // image's last strip (wave-uniform branch, executed once).
    if (r0 < 256 - RPS) {
        const float4 b = *reinterpret_cast<const float4*>(p + RPS * 256);
        acc += fabsf(b.x - a.x + EPS);
        acc += fabsf(b.y - a.y + EPS);
        acc += fabsf(b.z - a.z + EPS);
        acc += fabsf(b.w - a.w + EPS);
    }

    // wave reduction
    #pragma unroll
    for (int off = 32; off > 0; off >>= 1)
        acc += __shfl_down(acc, off, 64);

    __shared__ double sdata[WPB];
    if (lane == 0) sdata[wid] = (double)acc;
    __syncthreads();
    if (threadIdx.x == 0) {
        const double s = sdata[0] + sdata[1] + sdata[2] + sdata[3];
        atomicAdd(out, (float)(s / (double)NTOT));   // plain atomic, no fence
    }
}

extern "C" void kernel_launch(void* const* d_in, const int* in_sizes, int n_in,
                              void* d_out, int out_size, void* d_ws, size_t ws_size,
                              hipStream_t stream) {
    const float* x   = (const float*)d_in[0];
    float*       out = (float*)d_out;

    hipMemsetAsync(out, 0, sizeof(float), stream);   // 4 B, graph-safe
    tv_strip_kernel<<<BLOCKS, 256, 0, stream>>>(x, out);
}

// Round 9
// 39.063 us; speedup vs baseline: 1.1307x; 1.1307x over previous
//
#include <hip/hip_runtime.h>

// TotalVariation over [32,8,3,256,256] f32 = 768 images of 256x256.
// tv = (sum|dh+eps| + sum|dw+eps|) / N, N = 50331648.
//
// PROVEN BEST (R2: 38.72 us, R6: 38.71 us). Strip kernel -> per-block
// double partials -> dependent 1-block finalize.
// Each 64-lane wave owns a 64-row strip of one image; a row is exactly
// 64 float4s -> one wave-wide coalesced 1KB load per row. Walking down
// keeps the previous row in registers (vertical diffs need no re-load);
// cross-float4 horizontal diff via __shfl_down. Branch-free inner loop,
// unroll 4.
// Failed alternatives (measured): cooperative launch (launch error),
// in-kernel __threadfence + last-block reduce (87 us: fences collapse
// streaming BW), per-block atomicAdd into d_out + memset node (44-48 us:
// fill-node + atomic tail cost > finalize dispatch). Keep this shape.

#define EPS 1e-6f

static constexpr long long NTOT = 32LL * 8 * 3 * 256 * 256;  // 50,331,648
static constexpr int RPS    = 64;                  // rows per strip
static constexpr int STRIPS = 768 * (256 / RPS);   // 3072
static constexpr int WPB    = 4;                   // waves per block
static constexpr int BLOCKS = STRIPS / WPB;        // 768 = 3 blocks/CU

__global__ void __launch_bounds__(256)
tv_strip_kernel(const float* __restrict__ x, double* __restrict__ partial) {
    const int wid   = threadIdx.x >> 6;
    const int lane  = threadIdx.x & 63;
    const int strip = blockIdx.x * WPB + wid;        // 0 .. 3071
    const int img   = strip >> 2;                    // 4 strips per image
    const int r0    = (strip & 3) << 6;              // first row of strip

    const float* p = x + (size_t)img * 65536 + (size_t)r0 * 256 + lane * 4;

    float acc = 0.0f;
    float4 a = *reinterpret_cast<const float4*>(p);

    // rows r0+1 .. r0+63 are always inside the image: branch-free body.
    #pragma unroll 4
    for (int k = 1; k < RPS; ++k) {
        const float4 b = *reinterpret_cast<const float4*>(p + k * 256);
        // horizontal diffs for row r0+k-1
        acc += fabsf(a.y - a.x + EPS);
        acc += fabsf(a.z - a.y + EPS);
        acc += fabsf(a.w - a.z + EPS);
        const float nx = __shfl_down(a.x, 1, 64);    // neighbor float4's .x
        if (lane < 63) acc += fabsf(nx - a.w + EPS); // lane 63 = row end
        // vertical diffs row r0+k-1 -> r0+k
        acc += fabsf(b.x - a.x + EPS);
        acc += fabsf(b.y - a.y + EPS);
        acc += fabsf(b.z - a.z + EPS);
        acc += fabsf(b.w - a.w + EPS);
        a = b;
    }

    // epilogue: last row of the strip (r0+63)
    acc += fabsf(a.y - a.x + EPS);
    acc += fabsf(a.z - a.y + EPS);
    acc += fabsf(a.w - a.z + EPS);
    {
        const float nx = __shfl_down(a.x, 1, 64);
        if (lane < 63) acc += fabsf(nx - a.w + EPS);
    }
    // vertical diff into the next strip's first row, unless this is the
    // image's last strip (wave-uniform branch, executed once).
    if (r0 < 256 - RPS) {
        const float4 b = *reinterpret_cast<const float4*>(p + RPS * 256);
        acc += fabsf(b.x - a.x + EPS);
        acc += fabsf(b.y - a.y + EPS);
        acc += fabsf(b.z - a.z + EPS);
        acc += fabsf(b.w - a.w + EPS);
    }

    // wave reduction
    #pragma unroll
    for (int off = 32; off > 0; off >>= 1)
        acc += __shfl_down(acc, off, 64);

    __shared__ double sdata[WPB];
    if (lane == 0) sdata[wid] = (double)acc;
    __syncthreads();
    if (threadIdx.x == 0)
        partial[blockIdx.x] = sdata[0] + sdata[1] + sdata[2] + sdata[3];
}

__global__ void __launch_bounds__(256)
tv_final_kernel(const double* __restrict__ partial, float* __restrict__ out) {
    double s = 0.0;
    for (int i = threadIdx.x; i < BLOCKS; i += 256)
        s += partial[i];
    #pragma unroll
    for (int off = 32; off > 0; off >>= 1)
        s += __shfl_down(s, off, 64);
    __shared__ double sd[4];
    const int wid  = threadIdx.x >> 6;
    const int lane = threadIdx.x & 63;
    if (lane == 0) sd[wid] = s;
    __syncthreads();
    if (threadIdx.x == 0)
        out[0] = (float)((sd[0] + sd[1] + sd[2] + sd[3]) / (double)NTOT);
}

extern "C" void kernel_launch(void* const* d_in, const int* in_sizes, int n_in,
                              void* d_out, int out_size, void* d_ws, size_t ws_size,
                              hipStream_t stream) {
    const float* x   = (const float*)d_in[0];
    float*       out = (float*)d_out;
    double*      ws  = (double*)d_ws;   // BLOCKS doubles = 6 KB of scratch

    tv_strip_kernel<<<BLOCKS, 256, 0, stream>>>(x, ws);
    tv_final_kernel<<<1, 256, 0, stream>>>(ws, out);
}